// Round 4
// baseline (17470.280 us; speedup 1.0000x reference)
//
#include <hip/hip_runtime.h>
#include <hip/hip_bf16.h>
#include <math.h>

// B=512, T=16, DIN=7, D=512, L=2, H=8, HD=64, FF=2048
// Persistent mega-kernel (hand-rolled grid barrier, cooperative launch for
// co-residency) with a fallback to the verified round-2 multi-kernel path
// if the cooperative launch is rejected.

typedef __attribute__((__ext_vector_type__(8))) short short8;
typedef __attribute__((__ext_vector_type__(4))) float floatx4;

__device__ inline short8 as_short8(uint4 v){ union U{uint4 u; short8 s;} x; x.u=v; return x.s; }

__device__ inline ushort f2bf(float f){
    __hip_bfloat16 h = __float2bfloat16(f);
    ushort u; __builtin_memcpy(&u, &h, 2); return u;
}

#define NBLK 256

// Barrier state in device globals: zero-initialized at module load; the
// protocol restores counter to 0 after each barrier, and gen monotonically
// increases (persists harmlessly across graph replays).
__device__ unsigned g_bar[2] = {0u, 0u};

__device__ __forceinline__ void gridbar(){
    __syncthreads();
    if (threadIdx.x == 0){
        __threadfence();
        unsigned gen = __hip_atomic_load(&g_bar[1], __ATOMIC_RELAXED, __HIP_MEMORY_SCOPE_AGENT);
        unsigned arr = __hip_atomic_fetch_add(&g_bar[0], 1u, __ATOMIC_ACQ_REL, __HIP_MEMORY_SCOPE_AGENT) + 1u;
        if (arr == (unsigned)NBLK){
            __hip_atomic_store(&g_bar[0], 0u, __ATOMIC_RELAXED, __HIP_MEMORY_SCOPE_AGENT);
            __hip_atomic_store(&g_bar[1], gen + 1u, __ATOMIC_RELEASE, __HIP_MEMORY_SCOPE_AGENT);
        } else {
            while (__hip_atomic_load(&g_bar[1], __ATOMIC_ACQUIRE, __HIP_MEMORY_SCOPE_AGENT) == gen)
                __builtin_amdgcn_s_sleep(2);
        }
        __threadfence();
    }
    __syncthreads();
}

// ---------------------------------------------------------------------------
// Weight swizzle: fp32 W[K][N] -> bf16 16B groups of 8 k-consecutive values.
// Group linear index = (kb*4 + q)*N + n, holding W[kb*32+q*8 .. +7][n].
// ---------------------------------------------------------------------------
__global__ __launch_bounds__(256)
void swz_k(const float* __restrict__ qkv_w, const float* __restrict__ out_w,
           const float* __restrict__ ff1_w, const float* __restrict__ ff2_w,
           ushort* __restrict__ wsw)
{
    int id = blockIdx.z; int l = id & 1; int mi = id >> 1;
    int K, N; const float* src; size_t doff;
    if (mi == 0)      { K = 512;  N = 1536; src = qkv_w + (size_t)l*786432;  doff = (size_t)l*786432; }
    else if (mi == 1) { K = 512;  N = 512;  src = out_w + (size_t)l*262144;  doff = 1572864 + (size_t)l*262144; }
    else if (mi == 2) { K = 512;  N = 2048; src = ff1_w + (size_t)l*1048576; doff = 2097152 + (size_t)l*1048576; }
    else              { K = 2048; N = 512;  src = ff2_w + (size_t)l*1048576; doff = 4194304 + (size_t)l*1048576; }
    int n0 = blockIdx.x * 64, k0 = blockIdx.y * 32;
    if (n0 >= N || k0 >= K) return;
    __shared__ float tt[32][64];
    int tid = threadIdx.x;
    int c = tid & 63, r = tid >> 6;
    #pragma unroll
    for (int i = 0; i < 8; ++i)
        tt[r + i*4][c] = src[(size_t)(k0 + r + i*4)*N + n0 + c];
    __syncthreads();
    int q = tid >> 6, n = tid & 63;
    union { ushort s[8]; uint4 v; } pk;
    #pragma unroll
    for (int i = 0; i < 8; ++i) pk.s[i] = f2bf(tt[q*8 + i][n]);
    ((uint4*)(wsw + doff))[(size_t)((k0 >> 5)*4 + q)*N + n0 + n] = pk.v;
}

// ===========================================================================
// Fallback path: round-2 verified kernels
// ===========================================================================
__global__ __launch_bounds__(256)
void embed0_k(const float* __restrict__ x, const float* __restrict__ ip_w,
              const float* __restrict__ ip_b, float* __restrict__ h,
              __hip_bfloat16* __restrict__ hbf)
{
    int idx = blockIdx.x*256 + threadIdx.x;
    int b = idx >> 9, d = idx & 511;
    float pe = (d & 1) ? 1.0f : 0.0f;
    float acc = ip_b[d] + pe;
    #pragma unroll
    for (int i = 0; i < 7; ++i)
        acc += x[(b*16 + 0)*7 + i] * ip_w[i*512 + d];
    h[idx] = acc;
    hbf[idx] = __float2bfloat16(acc);
}

template<int MODE>
__global__ __launch_bounds__(256)
void gemm64_k(const __hip_bfloat16* __restrict__ A, const ushort* __restrict__ Wsw,
              const float* __restrict__ bias, int t,
              float* __restrict__ qbuf, __hip_bfloat16* __restrict__ kc,
              __hip_bfloat16* __restrict__ vc,
              __hip_bfloat16* __restrict__ obf, float* __restrict__ ofp,
              const float* __restrict__ resid)
{
    constexpr int K = (MODE == 2) ? 2048 : 512;
    constexpr int N = (MODE == 0) ? 1536 : (MODE == 1 ? 2048 : 512);
    __shared__ uint4 ldsA[256], ldsB[256];
    int tid = threadIdx.x, lane = tid & 63, w = tid >> 6;
    int n0 = blockIdx.x*64, m0 = blockIdx.y*64;
    const uint4* Ag = (const uint4*)A;
    const uint4* Bg = (const uint4*)Wsw;
    int am = tid >> 2, aq = tid & 3;
    int bq = tid >> 6, bn = tid & 63;
    int rh = w & 1, ch = w >> 1;
    int qd = lane >> 4, li = lane & 15;
    floatx4 a00 = {}, a01 = {}, a10 = {}, a11 = {};
    for (int kb = 0; kb < K/32; ++kb){
        ldsA[aq*64 + am] = Ag[(size_t)(m0 + am)*(K/8) + kb*4 + aq];
        ldsB[bq*64 + bn] = Bg[(size_t)(kb*4 + bq)*N + n0 + bn];
        __syncthreads();
        short8 af0 = as_short8(ldsA[qd*64 + rh*32 +      li]);
        short8 af1 = as_short8(ldsA[qd*64 + rh*32 + 16 + li]);
        short8 bf0 = as_short8(ldsB[qd*64 + ch*32 +      li]);
        short8 bf1 = as_short8(ldsB[qd*64 + ch*32 + 16 + li]);
        a00 = __builtin_amdgcn_mfma_f32_16x16x32_bf16(af0, bf0, a00, 0, 0, 0);
        a01 = __builtin_amdgcn_mfma_f32_16x16x32_bf16(af0, bf1, a01, 0, 0, 0);
        a10 = __builtin_amdgcn_mfma_f32_16x16x32_bf16(af1, bf0, a10, 0, 0, 0);
        a11 = __builtin_amdgcn_mfma_f32_16x16x32_bf16(af1, bf1, a11, 0, 0, 0);
        __syncthreads();
    }
    floatx4 accs[2][2] = {{a00, a01}, {a10, a11}};
    #pragma unroll
    for (int i = 0; i < 2; ++i){
        #pragma unroll
        for (int j = 0; j < 2; ++j){
            #pragma unroll
            for (int r = 0; r < 4; ++r){
                int m = m0 + rh*32 + i*16 + qd*4 + r;
                int n = n0 + ch*32 + j*16 + li;
                float v = accs[i][j][r] + bias[n];
                if (MODE == 0){
                    if (n < 512) qbuf[(size_t)m*512 + n] = v;
                    else if (n < 1024){ int z = n - 512;
                        kc[(((size_t)m*8 + (z >> 6))*16 + t)*64 + (z & 63)] = __float2bfloat16(v); }
                    else { int z = n - 1024;
                        vc[(((size_t)m*8 + (z >> 6))*16 + t)*64 + (z & 63)] = __float2bfloat16(v); }
                } else if (MODE == 1){
                    obf[(size_t)m*2048 + n] = __float2bfloat16(fmaxf(v, 0.0f));
                } else {
                    ofp[(size_t)m*512 + n] = v + resid[(size_t)m*512 + n];
                }
            }
        }
    }
}

__global__ __launch_bounds__(256)
void attn_k(const float* __restrict__ qbuf, const __hip_bfloat16* __restrict__ kc,
            const __hip_bfloat16* __restrict__ vc, __hip_bfloat16* __restrict__ attn_o, int t)
{
    int w = blockIdx.x*4 + (threadIdx.x >> 6);
    int lane = threadIdx.x & 63;
    int b = w >> 3, hh = w & 7;
    float qv = qbuf[(size_t)b*512 + hh*64 + lane];
    const __hip_bfloat16* kp = kc + ((size_t)b*8 + hh)*1024;
    const __hip_bfloat16* vp = vc + ((size_t)b*8 + hh)*1024;
    float m = -1e30f, s = 0.0f, o = 0.0f;
    for (int j = 0; j <= t; ++j){
        float p = qv * __bfloat162float(kp[j*64 + lane]);
        #pragma unroll
        for (int off = 32; off; off >>= 1) p += __shfl_xor(p, off);
        p *= 0.125f;
        float nm = fmaxf(m, p);
        float sc = expf(m - nm);
        float e  = expf(p - nm);
        s = s*sc + e;
        o = o*sc + e*__bfloat162float(vp[j*64 + lane]);
        m = nm;
    }
    attn_o[(size_t)b*512 + hh*64 + lane] = __float2bfloat16(o / s);
}

__global__ __launch_bounds__(256)
void outln_k(const __hip_bfloat16* __restrict__ Abf, const ushort* __restrict__ Wsw,
             const float* __restrict__ ob, const float* __restrict__ g,
             const float* __restrict__ be, float* __restrict__ h,
             __hip_bfloat16* __restrict__ hbf)
{
    __shared__ uint4 lA[64*17 + 1];
    __shared__ float redS[4][4][4], redQ[4][4][4];
    int tid = threadIdx.x, lane = tid & 63, w = tid >> 6;
    int m0 = blockIdx.x*16;
    const uint4* Ag = (const uint4*)Abf;
    #pragma unroll
    for (int it = 0; it < 4; ++it){
        int m = it*4 + w;
        lA[lane*17 + m] = Ag[(size_t)(m0 + m)*64 + lane];
    }
    __syncthreads();
    const uint4* Bg = (const uint4*)Wsw;
    int qd = lane >> 4, li = lane & 15;
    floatx4 acc[8] = {};
    for (int kb = 0; kb < 16; ++kb){
        short8 af = as_short8(lA[(kb*4 + qd)*17 + li]);
        #pragma unroll
        for (int c = 0; c < 8; ++c){
            int n = w*128 + c*16 + li;
            short8 bfv = as_short8(Bg[(size_t)(kb*4 + qd)*512 + n]);
            acc[c] = __builtin_amdgcn_mfma_f32_16x16x32_bf16(af, bfv, acc[c], 0, 0, 0);
        }
    }
    float v[8][4];
    float psum[4] = {}, psq[4] = {};
    #pragma unroll
    for (int c = 0; c < 8; ++c){
        #pragma unroll
        for (int r = 0; r < 4; ++r){
            int m = qd*4 + r, n = w*128 + c*16 + li;
            float xv = acc[c][r] + ob[n] + h[(size_t)(m0 + m)*512 + n];
            v[c][r] = xv; psum[r] += xv; psq[r] += xv*xv;
        }
    }
    #pragma unroll
    for (int off = 1; off < 16; off <<= 1){
        #pragma unroll
        for (int r = 0; r < 4; ++r){ psum[r] += __shfl_xor(psum[r], off); psq[r] += __shfl_xor(psq[r], off); }
    }
    if (li == 0){
        #pragma unroll
        for (int r = 0; r < 4; ++r){ redS[w][qd][r] = psum[r]; redQ[w][qd][r] = psq[r]; }
    }
    __syncthreads();
    float mean[4], rstd[4];
    #pragma unroll
    for (int r = 0; r < 4; ++r){
        float sm = redS[0][qd][r] + redS[1][qd][r] + redS[2][qd][r] + redS[3][qd][r];
        float sq = redQ[0][qd][r] + redQ[1][qd][r] + redQ[2][qd][r] + redQ[3][qd][r];
        mean[r] = sm * (1.0f/512.0f);
        float var = sq * (1.0f/512.0f) - mean[r]*mean[r];
        rstd[r] = rsqrtf(var + 1e-5f);
    }
    #pragma unroll
    for (int c = 0; c < 8; ++c){
        #pragma unroll
        for (int r = 0; r < 4; ++r){
            int m = qd*4 + r, n = w*128 + c*16 + li;
            float hn = (v[c][r] - mean[r])*rstd[r]*g[n] + be[n];
            h[(size_t)(m0 + m)*512 + n] = hn;
            hbf[(size_t)(m0 + m)*512 + n] = __float2bfloat16(hn);
        }
    }
}

__global__ __launch_bounds__(256)
void ln2he_k(const float* __restrict__ tmp, const float* __restrict__ g,
             const float* __restrict__ be, float* __restrict__ h,
             __hip_bfloat16* __restrict__ hbf,
             const float* __restrict__ hw, const float* __restrict__ hb,
             const float* __restrict__ x, const float* __restrict__ ip_w,
             const float* __restrict__ ip_b, float* __restrict__ out,
             int t, int dohead)
{
    int b = blockIdx.x, tid = threadIdx.x;
    __shared__ float red[4];
    __shared__ float hred[4][3];
    __shared__ float ybc[3];
    float x0 = tmp[(size_t)b*512 + tid];
    float x1 = tmp[(size_t)b*512 + 256 + tid];
    float s = x0 + x1;
    #pragma unroll
    for (int off = 32; off; off >>= 1) s += __shfl_xor(s, off);
    if ((tid & 63) == 0) red[tid >> 6] = s;
    __syncthreads();
    float mean = (red[0] + red[1] + red[2] + red[3]) * (1.0f/512.0f);
    float d0 = x0 - mean, d1 = x1 - mean;
    float vs = d0*d0 + d1*d1;
    #pragma unroll
    for (int off = 32; off; off >>= 1) vs += __shfl_xor(vs, off);
    __syncthreads();
    if ((tid & 63) == 0) red[tid >> 6] = vs;
    __syncthreads();
    float var = (red[0] + red[1] + red[2] + red[3]) * (1.0f/512.0f);
    float r = rsqrtf(var + 1e-5f);
    float n0_ = d0*r*g[tid]       + be[tid];
    float n1_ = d1*r*g[256 + tid] + be[256 + tid];
    if (!dohead){
        h[(size_t)b*512 + tid] = n0_;
        h[(size_t)b*512 + 256 + tid] = n1_;
        hbf[(size_t)b*512 + tid] = __float2bfloat16(n0_);
        hbf[(size_t)b*512 + 256 + tid] = __float2bfloat16(n1_);
        return;
    }
    float s0 = n0_*hw[tid*3]     + n1_*hw[(tid+256)*3];
    float s1 = n0_*hw[tid*3 + 1] + n1_*hw[(tid+256)*3 + 1];
    float s2 = n0_*hw[tid*3 + 2] + n1_*hw[(tid+256)*3 + 2];
    #pragma unroll
    for (int off = 32; off; off >>= 1){
        s0 += __shfl_xor(s0, off); s1 += __shfl_xor(s1, off); s2 += __shfl_xor(s2, off);
    }
    int w = tid >> 6;
    if ((tid & 63) == 0){ hred[w][0] = s0; hred[w][1] = s1; hred[w][2] = s2; }
    __syncthreads();
    if (tid < 3){
        float y = hred[0][tid] + hred[1][tid] + hred[2][tid] + hred[3][tid] + hb[tid];
        out[((size_t)b*16 + t)*3 + tid] = y;
        ybc[tid] = y;
    }
    __syncthreads();
    if (t < 15){
        float y0 = ybc[0], y1 = ybc[1], y2 = ybc[2];
        #pragma unroll
        for (int half = 0; half < 2; ++half){
            int d = tid + half*256;
            int e = d & ~1;
            float div = expf(-(float)e * (9.210340371976184f / 512.0f));
            float arg = (float)(t + 1) * div;
            float pe = (d & 1) ? cosf(arg) : sinf(arg);
            float acc = ip_b[d] + pe;
            #pragma unroll
            for (int i = 0; i < 4; ++i)
                acc += x[((size_t)b*16 + t + 1)*7 + i] * ip_w[i*512 + d];
            acc += y0*ip_w[4*512 + d] + y1*ip_w[5*512 + d] + y2*ip_w[6*512 + d];
            h[(size_t)b*512 + d] = acc;
            hbf[(size_t)b*512 + d] = __float2bfloat16(acc);
        }
    }
}

// ===========================================================================
// Mega kernel: persistent, hand-rolled grid barrier
// ===========================================================================
__device__ __forceinline__ void gemm_tile(
    const uint4* __restrict__ Ag, const uint4* __restrict__ Bg,
    int Kg, int N, int kb0, int kb1, int m0, int n0, int tid,
    floatx4 acc[2][2], uint4* ldsA, uint4* ldsB)
{
    int lane = tid & 63, w = tid >> 6;
    int am = tid >> 2, aq = tid & 3;
    int bq = w, bn = tid & 63;
    int rh = w & 1, ch = w >> 1;
    int qd = lane >> 4, li = lane & 15;
    for (int kb = kb0; kb < kb1; ++kb){
        __syncthreads();
        ldsA[aq*64 + am] = Ag[(size_t)(m0 + am)*Kg + kb*4 + aq];
        ldsB[bq*64 + bn] = Bg[(size_t)(kb*4 + bq)*N + n0 + bn];
        __syncthreads();
        short8 af0 = as_short8(ldsA[qd*64 + rh*32 +      li]);
        short8 af1 = as_short8(ldsA[qd*64 + rh*32 + 16 + li]);
        short8 bf0 = as_short8(ldsB[qd*64 + ch*32 +      li]);
        short8 bf1 = as_short8(ldsB[qd*64 + ch*32 + 16 + li]);
        acc[0][0] = __builtin_amdgcn_mfma_f32_16x16x32_bf16(af0, bf0, acc[0][0], 0, 0, 0);
        acc[0][1] = __builtin_amdgcn_mfma_f32_16x16x32_bf16(af0, bf1, acc[0][1], 0, 0, 0);
        acc[1][0] = __builtin_amdgcn_mfma_f32_16x16x32_bf16(af1, bf0, acc[1][0], 0, 0, 0);
        acc[1][1] = __builtin_amdgcn_mfma_f32_16x16x32_bf16(af1, bf1, acc[1][1], 0, 0, 0);
    }
}

__global__ __launch_bounds__(256)
void mega_k(const float* __restrict__ x, const ushort* __restrict__ wsw,
            const float* __restrict__ ip_w, const float* __restrict__ ip_b,
            const float* __restrict__ qkv_b, const float* __restrict__ out_b,
            const float* __restrict__ ln1_s, const float* __restrict__ ln1_b,
            const float* __restrict__ ff_b1, const float* __restrict__ ff_b2,
            const float* __restrict__ ln2_s, const float* __restrict__ ln2_b,
            const float* __restrict__ hw, const float* __restrict__ hb,
            float* __restrict__ out,
            float* __restrict__ pbuf, float* __restrict__ h,
            __hip_bfloat16* __restrict__ hbf, __hip_bfloat16* __restrict__ attnbf,
            __hip_bfloat16* __restrict__ ffbf,
            __hip_bfloat16* __restrict__ kc, __hip_bfloat16* __restrict__ vc)
{
    __shared__ union {
        struct { uint4 a[256]; uint4 b[256]; } g;
        uint4 slab[64*17 + 1];
    } sh;
    __shared__ float redS[4][4][4], redQ[4][4][4];
    __shared__ float redA[4];
    __shared__ float hred[4][3];
    __shared__ float ybc[3];

    float* qbuf = pbuf + 262144;   // alias: dead before ff2 partial-1 write

    int blk = blockIdx.x, tid = threadIdx.x;
    int lane = tid & 63, w = tid >> 6;
    int rh = w & 1, ch = w >> 1;
    int qd = lane >> 4, li = lane & 15;

    // ---- t=0 embed
    #pragma unroll
    for (int rr = 0; rr < 2; ++rr){
        int b = blk*2 + rr;
        #pragma unroll
        for (int half = 0; half < 2; ++half){
            int d = tid + half*256;
            float pe = (d & 1) ? 1.0f : 0.0f;
            float acc = ip_b[d] + pe;
            #pragma unroll
            for (int i = 0; i < 7; ++i)
                acc += x[(b*16 + 0)*7 + i] * ip_w[i*512 + d];
            h[b*512 + d] = acc;
            hbf[b*512 + d] = __float2bfloat16(acc);
        }
    }
    gridbar();

    for (int t = 0; t < 16; ++t){
        for (int l = 0; l < 2; ++l){
            // -------- P1: QKV GEMM (192 tiles) --------
            if (blk < 192){
                int m0 = (blk / 24) * 64, n0 = (blk % 24) * 64;
                floatx4 acc[2][2] = {};
                gemm_tile((const uint4*)hbf, (const uint4*)(wsw + (size_t)l*786432),
                          64, 1536, 0, 16, m0, n0, tid, acc, sh.g.a, sh.g.b);
                const float* qb = qkv_b + l*1536;
                __hip_bfloat16* kcl = kc + (size_t)l*4194304;
                __hip_bfloat16* vcl = vc + (size_t)l*4194304;
                #pragma unroll
                for (int i = 0; i < 2; ++i){
                    #pragma unroll
                    for (int j = 0; j < 2; ++j){
                        #pragma unroll
                        for (int r = 0; r < 4; ++r){
                            int m = m0 + rh*32 + i*16 + qd*4 + r;
                            int n = n0 + ch*32 + j*16 + li;
                            float v = acc[i][j][r] + qb[n];
                            if (n < 512){
                                qbuf[m*512 + n] = v;
                            } else if (n < 1024){
                                int z = n - 512;
                                kcl[((m*8 + (z >> 6))*16 + t)*64 + (z & 63)] = __float2bfloat16(v);
                            } else {
                                int z = n - 1024;
                                vcl[((m*8 + (z >> 6))*16 + t)*64 + (z & 63)] = __float2bfloat16(v);
                            }
                        }
                    }
                }
            }
            gridbar();

            // -------- P2: attention --------
            {
                const __hip_bfloat16* kcl = kc + (size_t)l*4194304;
                const __hip_bfloat16* vcl = vc + (size_t)l*4194304;
                #pragma unroll
                for (int p = 0; p < 4; ++p){
                    int pair = (blk*4 + w)*4 + p;
                    int b = pair >> 3, hh = pair & 7;
                    float qv = qbuf[b*512 + hh*64 + lane];
                    const __hip_bfloat16* kp = kcl + ((size_t)b*8 + hh)*1024;
                    const __hip_bfloat16* vp = vcl + ((size_t)b*8 + hh)*1024;
                    float m_ = -1e30f, s_ = 0.0f, o_ = 0.0f;
                    for (int j = 0; j <= t; ++j){
                        float pq = qv * __bfloat162float(kp[j*64 + lane]);
                        #pragma unroll
                        for (int off = 32; off; off >>= 1) pq += __shfl_xor(pq, off);
                        pq *= 0.125f;
                        float nm = fmaxf(m_, pq);
                        float sc = expf(m_ - nm);
                        float e  = expf(pq - nm);
                        s_ = s_*sc + e;
                        o_ = o_*sc + e*__bfloat162float(vp[j*64 + lane]);
                        m_ = nm;
                    }
                    attnbf[b*512 + hh*64 + lane] = __float2bfloat16(o_ / s_);
                }
            }
            gridbar();

            // -------- P3: out-proj + bias + resid + LN1 (32 row-blocks) ----
            if (blk < 32){
                int m0 = blk*16;
                const uint4* Ag = (const uint4*)attnbf;
                #pragma unroll
                for (int it = 0; it < 4; ++it){
                    int m = it*4 + w;
                    sh.slab[lane*17 + m] = Ag[(size_t)(m0 + m)*64 + lane];
                }
                __syncthreads();
                const uint4* Bg = (const uint4*)(wsw + 1572864 + (size_t)l*262144);
                floatx4 acc[8] = {};
                for (int kb = 0; kb < 16; ++kb){
                    short8 af = as_short8(sh.slab[(kb*4 + qd)*17 + li]);
                    #pragma unroll
                    for (int c = 0; c < 8; ++c){
                        int n = w*128 + c*16 + li;
                        short8 bfv = as_short8(Bg[(size_t)(kb*4 + qd)*512 + n]);
                        acc[c] = __builtin_amdgcn_mfma_f32_16x16x32_bf16(af, bfv, acc[c], 0, 0, 0);
                    }
                }
                const float* ob = out_b + l*512;
                const float* g  = ln1_s + l*512;
                const float* be = ln1_b + l*512;
                float v[8][4];
                float psum[4] = {}, psq[4] = {};
                #pragma unroll
                for (int c = 0; c < 8; ++c){
                    #pragma unroll
                    for (int r = 0; r < 4; ++r){
                        int m = qd*4 + r, n = w*128 + c*16 + li;
                        float xv = acc[c][r] + ob[n] + h[(size_t)(m0 + m)*512 + n];
                        v[c][r] = xv; psum[r] += xv; psq[r] += xv*xv;
                    }
                }
                #pragma unroll
                for (int off = 1; off < 16; off <<= 1){
                    #pragma unroll
                    for (int r = 0; r < 4; ++r){ psum[r] += __shfl_xor(psum[r], off); psq[r] += __shfl_xor(psq[r], off); }
                }
                if (li == 0){
                    #pragma unroll
                    for (int r = 0; r < 4; ++r){ redS[w][qd][r] = psum[r]; redQ[w][qd][r] = psq[r]; }
                }
                __syncthreads();
                float mean[4], rstd[4];
                #pragma unroll
                for (int r = 0; r < 4; ++r){
                    float sm = redS[0][qd][r] + redS[1][qd][r] + redS[2][qd][r] + redS[3][qd][r];
                    float sq = redQ[0][qd][r] + redQ[1][qd][r] + redQ[2][qd][r] + redQ[3][qd][r];
                    mean[r] = sm * (1.0f/512.0f);
                    float var = sq * (1.0f/512.0f) - mean[r]*mean[r];
                    rstd[r] = rsqrtf(var + 1e-5f);
                }
                #pragma unroll
                for (int c = 0; c < 8; ++c){
                    #pragma unroll
                    for (int r = 0; r < 4; ++r){
                        int m = qd*4 + r, n = w*128 + c*16 + li;
                        float hn = (v[c][r] - mean[r])*rstd[r]*g[n] + be[n];
                        h[(size_t)(m0 + m)*512 + n] = hn;
                        hbf[(size_t)(m0 + m)*512 + n] = __float2bfloat16(hn);
                    }
                }
            }
            gridbar();

            // -------- P4: FF1 + relu (256 tiles) --------
            {
                int m0 = (blk >> 5) * 64, n0 = (blk & 31) * 64;
                floatx4 acc[2][2] = {};
                gemm_tile((const uint4*)hbf, (const uint4*)(wsw + 2097152 + (size_t)l*1048576),
                          64, 2048, 0, 16, m0, n0, tid, acc, sh.g.a, sh.g.b);
                const float* fb = ff_b1 + l*2048;
                #pragma unroll
                for (int i = 0; i < 2; ++i){
                    #pragma unroll
                    for (int j = 0; j < 2; ++j){
                        #pragma unroll
                        for (int r = 0; r < 4; ++r){
                            int m = m0 + rh*32 + i*16 + qd*4 + r;
                            int n = n0 + ch*32 + j*16 + li;
                            float v = acc[i][j][r] + fb[n];
                            ffbf[(size_t)m*2048 + n] = __float2bfloat16(fmaxf(v, 0.0f));
                        }
                    }
                }
            }
            gridbar();

            // -------- P5: FF2 split-K=2 (128 blocks) --------
            if (blk < 128){
                int tile = blk >> 1, ks = blk & 1;
                int m0 = (tile >> 3) * 64, n0 = (tile & 7) * 64;
                floatx4 acc[2][2] = {};
                gemm_tile((const uint4*)ffbf, (const uint4*)(wsw + 4194304 + (size_t)l*1048576),
                          256, 512, ks*32, ks*32 + 32, m0, n0, tid, acc, sh.g.a, sh.g.b);
                float* pp = pbuf + ks*262144;
                #pragma unroll
                for (int i = 0; i < 2; ++i){
                    #pragma unroll
                    for (int j = 0; j < 2; ++j){
                        #pragma unroll
                        for (int r = 0; r < 4; ++r){
                            int m = m0 + rh*32 + i*16 + qd*4 + r;
                            int n = n0 + ch*32 + j*16 + li;
                            pp[m*512 + n] = acc[i][j][r];
                        }
                    }
                }
            }
            gridbar();

            // -------- P6: LN2 (+head+embed on l==1) --------
            {
                const float* g  = ln2_s + l*512;
                const float* be = ln2_b + l*512;
                const float* fb = ff_b2 + l*512;
                #pragma unroll
                for (int rr = 0; rr < 2; ++rr){
                    int b = blk*2 + rr;
                    float v0 = pbuf[b*512 + tid]       + pbuf[262144 + b*512 + tid]
                             + fb[tid]       + h[b*512 + tid];
                    float v1 = pbuf[b*512 + 256 + tid] + pbuf[262144 + b*512 + 256 + tid]
                             + fb[256 + tid] + h[b*512 + 256 + tid];
                    float s = v0 + v1;
                    #pragma unroll
                    for (int off = 32; off; off >>= 1) s += __shfl_xor(s, off);
                    __syncthreads();
                    if ((tid & 63) == 0) redA[w] = s;
                    __syncthreads();
                    float mean = (redA[0] + redA[1] + redA[2] + redA[3]) * (1.0f/512.0f);
                    float d0 = v0 - mean, d1 = v1 - mean;
                    float vs = d0*d0 + d1*d1;
                    #pragma unroll
                    for (int off = 32; off; off >>= 1) vs += __shfl_xor(vs, off);
                    __syncthreads();
                    if ((tid & 63) == 0) redA[w] = vs;
                    __syncthreads();
                    float var = (redA[0] + redA[1] + redA[2] + redA[3]) * (1.0f/512.0f);
                    float r = rsqrtf(var + 1e-5f);
                    float n0_ = d0*r*g[tid]       + be[tid];
                    float n1_ = d1*r*g[256 + tid] + be[256 + tid];
                    if (l == 0){
                        h[b*512 + tid]       = n0_;
                        h[b*512 + 256 + tid] = n1_;
                        hbf[b*512 + tid]       = __float2bfloat16(n0_);
                        hbf[b*512 + 256 + tid] = __float2bfloat16(n1_);
                    } else {
                        float s0 = n0_*hw[tid*3]     + n1_*hw[(tid+256)*3];
                        float s1 = n0_*hw[tid*3 + 1] + n1_*hw[(tid+256)*3 + 1];
                        float s2 = n0_*hw[tid*3 + 2] + n1_*hw[(tid+256)*3 + 2];
                        #pragma unroll
                        for (int off = 32; off; off >>= 1){
                            s0 += __shfl_xor(s0, off);
                            s1 += __shfl_xor(s1, off);
                            s2 += __shfl_xor(s2, off);
                        }
                        __syncthreads();
                        if ((tid & 63) == 0){ hred[w][0] = s0; hred[w][1] = s1; hred[w][2] = s2; }
                        __syncthreads();
                        if (tid < 3){
                            float y = hred[0][tid] + hred[1][tid] + hred[2][tid] + hred[3][tid] + hb[tid];
                            out[(b*16 + t)*3 + tid] = y;
                            ybc[tid] = y;
                        }
                        __syncthreads();
                        if (t < 15){
                            float y0 = ybc[0], y1 = ybc[1], y2 = ybc[2];
                            #pragma unroll
                            for (int half = 0; half < 2; ++half){
                                int d = tid + half*256;
                                int e = d & ~1;
                                float div = expf(-(float)e * (9.210340371976184f / 512.0f));
                                float arg = (float)(t + 1) * div;
                                float pe = (d & 1) ? cosf(arg) : sinf(arg);
                                float acc = ip_b[d] + pe;
                                #pragma unroll
                                for (int i = 0; i < 4; ++i)
                                    acc += x[(b*16 + t + 1)*7 + i] * ip_w[i*512 + d];
                                acc += y0*ip_w[4*512 + d] + y1*ip_w[5*512 + d] + y2*ip_w[6*512 + d];
                                h[b*512 + d] = acc;
                                hbf[b*512 + d] = __float2bfloat16(acc);
                            }
                        }
                        __syncthreads();
                    }
                }
            }
            gridbar();
        }
    }
}

// ---------------------------------------------------------------------------
extern "C" void kernel_launch(void* const* d_in, const int* in_sizes, int n_in,
                              void* d_out, int out_size, void* d_ws, size_t ws_size,
                              hipStream_t stream)
{
    const float* x     = (const float*)d_in[0];
    const float* ip_w  = (const float*)d_in[1];
    const float* ip_b  = (const float*)d_in[2];
    const float* qkv_w = (const float*)d_in[3];
    const float* qkv_b = (const float*)d_in[4];
    const float* out_w = (const float*)d_in[5];
    const float* out_b = (const float*)d_in[6];
    const float* ln1_s = (const float*)d_in[7];
    const float* ln1_b = (const float*)d_in[8];
    const float* ff_w1 = (const float*)d_in[9];
    const float* ff_b1 = (const float*)d_in[10];
    const float* ff_w2 = (const float*)d_in[11];
    const float* ff_b2 = (const float*)d_in[12];
    const float* ln2_s = (const float*)d_in[13];
    const float* ln2_b = (const float*)d_in[14];
    const float* hw    = (const float*)d_in[15];
    const float* hb    = (const float*)d_in[16];
    float* out = (float*)d_out;

    // ws layout (bytes): wsw 12,582,912 | pbuf 2M | h 1M | hbf 0.5M |
    //                    attnbf 0.5M | ffbf 2M | kc 16M | vc 16M = 50 MB
    ushort* wsw = (ushort*)d_ws;
    float* pbuf = (float*)((char*)d_ws + 12582912);
    float* h    = pbuf + 524288;
    __hip_bfloat16* hbf    = (__hip_bfloat16*)(h + 262144);
    __hip_bfloat16* attnbf = hbf + 262144;
    __hip_bfloat16* ffbf   = attnbf + 262144;
    __hip_bfloat16* kc     = ffbf + 1048576;
    __hip_bfloat16* vc     = kc + 8388608;
    float* tmp  = pbuf;
    float* qbuf = pbuf + 262144;
    const int CPL = 4194304;

    swz_k<<<dim3(32, 64, 8), 256, 0, stream>>>(qkv_w, out_w, ff_w1, ff_w2, wsw);

    void* args[] = {
        (void*)&x, (void*)&wsw, (void*)&ip_w, (void*)&ip_b,
        (void*)&qkv_b, (void*)&out_b, (void*)&ln1_s, (void*)&ln1_b,
        (void*)&ff_b1, (void*)&ff_b2, (void*)&ln2_s, (void*)&ln2_b,
        (void*)&hw, (void*)&hb, (void*)&out,
        (void*)&pbuf, (void*)&h, (void*)&hbf, (void*)&attnbf, (void*)&ffbf,
        (void*)&kc, (void*)&vc
    };
    hipError_t err = hipLaunchCooperativeKernel((void*)mega_k, dim3(NBLK), dim3(256),
                                                args, 0, stream);
    if (err != hipSuccess){
        // Fallback: verified round-2 multi-kernel path.
        embed0_k<<<1024, 256, 0, stream>>>(x, ip_w, ip_b, h, hbf);
        for (int t = 0; t < 16; ++t){
            for (int l = 0; l < 2; ++l){
                gemm64_k<0><<<dim3(24, 8), 256, 0, stream>>>(
                    hbf, wsw + (size_t)l*786432, qkv_b + l*1536, t,
                    qbuf, kc + (size_t)l*CPL, vc + (size_t)l*CPL,
                    nullptr, nullptr, nullptr);
                attn_k<<<1024, 256, 0, stream>>>(qbuf, kc + (size_t)l*CPL, vc + (size_t)l*CPL, attnbf, t);
                outln_k<<<32, 256, 0, stream>>>(
                    attnbf, wsw + 1572864 + (size_t)l*262144, out_b + l*512,
                    ln1_s + l*512, ln1_b + l*512, h, hbf);
                gemm64_k<1><<<dim3(32, 8), 256, 0, stream>>>(
                    hbf, wsw + 2097152 + (size_t)l*1048576, ff_b1 + l*2048, t,
                    nullptr, nullptr, nullptr, ffbf, nullptr, nullptr);
                gemm64_k<2><<<dim3(8, 8), 256, 0, stream>>>(
                    ffbf, wsw + 4194304 + (size_t)l*1048576, ff_b2 + l*512, t,
                    nullptr, nullptr, nullptr, nullptr, tmp, h);
                ln2he_k<<<512, 256, 0, stream>>>(
                    tmp, ln2_s + l*512, ln2_b + l*512, h, hbf,
                    hw, hb, x, ip_w, ip_b, out, t, l == 1);
            }
        }
    }
}

// Round 5
// 7120.271 us; speedup vs baseline: 2.4536x; 2.4536x over previous
//
#include <hip/hip_runtime.h>
#include <hip/hip_bf16.h>
#include <math.h>

// B=512, T=16, DIN=7, D=512, L=2, H=8, HD=64, FF=2048
// Persistent mega-kernel (hand-rolled grid barrier, cooperative launch for
// co-residency) with a fallback to the verified round-2 multi-kernel path
// if the cooperative launch is rejected.
//
// R5 change vs R4: gridbar() rewritten — relaxed spin + single acq fence
// (R4 spun with ACQUIRE loads + 2x __threadfence per barrier -> L2
// invalidate storm, ~85us/barrier, 682MB overfetch).

typedef __attribute__((__ext_vector_type__(8))) short short8;
typedef __attribute__((__ext_vector_type__(4))) float floatx4;

__device__ inline short8 as_short8(uint4 v){ union U{uint4 u; short8 s;} x; x.u=v; return x.s; }

__device__ inline ushort f2bf(float f){
    __hip_bfloat16 h = __float2bfloat16(f);
    ushort u; __builtin_memcpy(&u, &h, 2); return u;
}

#define NBLK 256

// Barrier state in device globals: zero-initialized at module load; the
// protocol restores counter to 0 after each barrier, and gen monotonically
// increases (persists harmlessly across graph replays).
__device__ unsigned g_bar[2] = {0u, 0u};

__device__ __forceinline__ void gridbar(){
    __syncthreads();
    if (threadIdx.x == 0){
        unsigned gen = __hip_atomic_load(&g_bar[1], __ATOMIC_RELAXED, __HIP_MEMORY_SCOPE_AGENT);
        // ACQ_REL RMW: releases this block's prior writes, acquires others'.
        unsigned arr = __hip_atomic_fetch_add(&g_bar[0], 1u, __ATOMIC_ACQ_REL, __HIP_MEMORY_SCOPE_AGENT) + 1u;
        if (arr == (unsigned)NBLK){
            __hip_atomic_store(&g_bar[0], 0u, __ATOMIC_RELAXED, __HIP_MEMORY_SCOPE_AGENT);
            __hip_atomic_store(&g_bar[1], gen + 1u, __ATOMIC_RELEASE, __HIP_MEMORY_SCOPE_AGENT);
        } else {
            // RELAXED polls: no cache-maintenance per iteration.
            while (__hip_atomic_load(&g_bar[1], __ATOMIC_RELAXED, __HIP_MEMORY_SCOPE_AGENT) == gen)
                __builtin_amdgcn_s_sleep(8);
        }
        // One acquire fence: invalidate stale cache lines once per barrier.
        __builtin_amdgcn_fence(__ATOMIC_ACQUIRE, "agent");
    }
    __syncthreads();
}

// ---------------------------------------------------------------------------
// Weight swizzle: fp32 W[K][N] -> bf16 16B groups of 8 k-consecutive values.
// Group linear index = (kb*4 + q)*N + n, holding W[kb*32+q*8 .. +7][n].
// ---------------------------------------------------------------------------
__global__ __launch_bounds__(256)
void swz_k(const float* __restrict__ qkv_w, const float* __restrict__ out_w,
           const float* __restrict__ ff1_w, const float* __restrict__ ff2_w,
           ushort* __restrict__ wsw)
{
    int id = blockIdx.z; int l = id & 1; int mi = id >> 1;
    int K, N; const float* src; size_t doff;
    if (mi == 0)      { K = 512;  N = 1536; src = qkv_w + (size_t)l*786432;  doff = (size_t)l*786432; }
    else if (mi == 1) { K = 512;  N = 512;  src = out_w + (size_t)l*262144;  doff = 1572864 + (size_t)l*262144; }
    else if (mi == 2) { K = 512;  N = 2048; src = ff1_w + (size_t)l*1048576; doff = 2097152 + (size_t)l*1048576; }
    else              { K = 2048; N = 512;  src = ff2_w + (size_t)l*1048576; doff = 4194304 + (size_t)l*1048576; }
    int n0 = blockIdx.x * 64, k0 = blockIdx.y * 32;
    if (n0 >= N || k0 >= K) return;
    __shared__ float tt[32][64];
    int tid = threadIdx.x;
    int c = tid & 63, r = tid >> 6;
    #pragma unroll
    for (int i = 0; i < 8; ++i)
        tt[r + i*4][c] = src[(size_t)(k0 + r + i*4)*N + n0 + c];
    __syncthreads();
    int q = tid >> 6, n = tid & 63;
    union { ushort s[8]; uint4 v; } pk;
    #pragma unroll
    for (int i = 0; i < 8; ++i) pk.s[i] = f2bf(tt[q*8 + i][n]);
    ((uint4*)(wsw + doff))[(size_t)((k0 >> 5)*4 + q)*N + n0 + n] = pk.v;
}

// ===========================================================================
// Fallback path: round-2 verified kernels
// ===========================================================================
__global__ __launch_bounds__(256)
void embed0_k(const float* __restrict__ x, const float* __restrict__ ip_w,
              const float* __restrict__ ip_b, float* __restrict__ h,
              __hip_bfloat16* __restrict__ hbf)
{
    int idx = blockIdx.x*256 + threadIdx.x;
    int b = idx >> 9, d = idx & 511;
    float pe = (d & 1) ? 1.0f : 0.0f;
    float acc = ip_b[d] + pe;
    #pragma unroll
    for (int i = 0; i < 7; ++i)
        acc += x[(b*16 + 0)*7 + i] * ip_w[i*512 + d];
    h[idx] = acc;
    hbf[idx] = __float2bfloat16(acc);
}

template<int MODE>
__global__ __launch_bounds__(256)
void gemm64_k(const __hip_bfloat16* __restrict__ A, const ushort* __restrict__ Wsw,
              const float* __restrict__ bias, int t,
              float* __restrict__ qbuf, __hip_bfloat16* __restrict__ kc,
              __hip_bfloat16* __restrict__ vc,
              __hip_bfloat16* __restrict__ obf, float* __restrict__ ofp,
              const float* __restrict__ resid)
{
    constexpr int K = (MODE == 2) ? 2048 : 512;
    constexpr int N = (MODE == 0) ? 1536 : (MODE == 1 ? 2048 : 512);
    __shared__ uint4 ldsA[256], ldsB[256];
    int tid = threadIdx.x, lane = tid & 63, w = tid >> 6;
    int n0 = blockIdx.x*64, m0 = blockIdx.y*64;
    const uint4* Ag = (const uint4*)A;
    const uint4* Bg = (const uint4*)Wsw;
    int am = tid >> 2, aq = tid & 3;
    int bq = tid >> 6, bn = tid & 63;
    int rh = w & 1, ch = w >> 1;
    int qd = lane >> 4, li = lane & 15;
    floatx4 a00 = {}, a01 = {}, a10 = {}, a11 = {};
    for (int kb = 0; kb < K/32; ++kb){
        ldsA[aq*64 + am] = Ag[(size_t)(m0 + am)*(K/8) + kb*4 + aq];
        ldsB[bq*64 + bn] = Bg[(size_t)(kb*4 + bq)*N + n0 + bn];
        __syncthreads();
        short8 af0 = as_short8(ldsA[qd*64 + rh*32 +      li]);
        short8 af1 = as_short8(ldsA[qd*64 + rh*32 + 16 + li]);
        short8 bf0 = as_short8(ldsB[qd*64 + ch*32 +      li]);
        short8 bf1 = as_short8(ldsB[qd*64 + ch*32 + 16 + li]);
        a00 = __builtin_amdgcn_mfma_f32_16x16x32_bf16(af0, bf0, a00, 0, 0, 0);
        a01 = __builtin_amdgcn_mfma_f32_16x16x32_bf16(af0, bf1, a01, 0, 0, 0);
        a10 = __builtin_amdgcn_mfma_f32_16x16x32_bf16(af1, bf0, a10, 0, 0, 0);
        a11 = __builtin_amdgcn_mfma_f32_16x16x32_bf16(af1, bf1, a11, 0, 0, 0);
        __syncthreads();
    }
    floatx4 accs[2][2] = {{a00, a01}, {a10, a11}};
    #pragma unroll
    for (int i = 0; i < 2; ++i){
        #pragma unroll
        for (int j = 0; j < 2; ++j){
            #pragma unroll
            for (int r = 0; r < 4; ++r){
                int m = m0 + rh*32 + i*16 + qd*4 + r;
                int n = n0 + ch*32 + j*16 + li;
                float v = accs[i][j][r] + bias[n];
                if (MODE == 0){
                    if (n < 512) qbuf[(size_t)m*512 + n] = v;
                    else if (n < 1024){ int z = n - 512;
                        kc[(((size_t)m*8 + (z >> 6))*16 + t)*64 + (z & 63)] = __float2bfloat16(v); }
                    else { int z = n - 1024;
                        vc[(((size_t)m*8 + (z >> 6))*16 + t)*64 + (z & 63)] = __float2bfloat16(v); }
                } else if (MODE == 1){
                    obf[(size_t)m*2048 + n] = __float2bfloat16(fmaxf(v, 0.0f));
                } else {
                    ofp[(size_t)m*512 + n] = v + resid[(size_t)m*512 + n];
                }
            }
        }
    }
}

__global__ __launch_bounds__(256)
void attn_k(const float* __restrict__ qbuf, const __hip_bfloat16* __restrict__ kc,
            const __hip_bfloat16* __restrict__ vc, __hip_bfloat16* __restrict__ attn_o, int t)
{
    int w = blockIdx.x*4 + (threadIdx.x >> 6);
    int lane = threadIdx.x & 63;
    int b = w >> 3, hh = w & 7;
    float qv = qbuf[(size_t)b*512 + hh*64 + lane];
    const __hip_bfloat16* kp = kc + ((size_t)b*8 + hh)*1024;
    const __hip_bfloat16* vp = vc + ((size_t)b*8 + hh)*1024;
    float m = -1e30f, s = 0.0f, o = 0.0f;
    for (int j = 0; j <= t; ++j){
        float p = qv * __bfloat162float(kp[j*64 + lane]);
        #pragma unroll
        for (int off = 32; off; off >>= 1) p += __shfl_xor(p, off);
        p *= 0.125f;
        float nm = fmaxf(m, p);
        float sc = expf(m - nm);
        float e  = expf(p - nm);
        s = s*sc + e;
        o = o*sc + e*__bfloat162float(vp[j*64 + lane]);
        m = nm;
    }
    attn_o[(size_t)b*512 + hh*64 + lane] = __float2bfloat16(o / s);
}

__global__ __launch_bounds__(256)
void outln_k(const __hip_bfloat16* __restrict__ Abf, const ushort* __restrict__ Wsw,
             const float* __restrict__ ob, const float* __restrict__ g,
             const float* __restrict__ be, float* __restrict__ h,
             __hip_bfloat16* __restrict__ hbf)
{
    __shared__ uint4 lA[64*17 + 1];
    __shared__ float redS[4][4][4], redQ[4][4][4];
    int tid = threadIdx.x, lane = tid & 63, w = tid >> 6;
    int m0 = blockIdx.x*16;
    const uint4* Ag = (const uint4*)Abf;
    #pragma unroll
    for (int it = 0; it < 4; ++it){
        int m = it*4 + w;
        lA[lane*17 + m] = Ag[(size_t)(m0 + m)*64 + lane];
    }
    __syncthreads();
    const uint4* Bg = (const uint4*)Wsw;
    int qd = lane >> 4, li = lane & 15;
    floatx4 acc[8] = {};
    for (int kb = 0; kb < 16; ++kb){
        short8 af = as_short8(lA[(kb*4 + qd)*17 + li]);
        #pragma unroll
        for (int c = 0; c < 8; ++c){
            int n = w*128 + c*16 + li;
            short8 bfv = as_short8(Bg[(size_t)(kb*4 + qd)*512 + n]);
            acc[c] = __builtin_amdgcn_mfma_f32_16x16x32_bf16(af, bfv, acc[c], 0, 0, 0);
        }
    }
    float v[8][4];
    float psum[4] = {}, psq[4] = {};
    #pragma unroll
    for (int c = 0; c < 8; ++c){
        #pragma unroll
        for (int r = 0; r < 4; ++r){
            int m = qd*4 + r, n = w*128 + c*16 + li;
            float xv = acc[c][r] + ob[n] + h[(size_t)(m0 + m)*512 + n];
            v[c][r] = xv; psum[r] += xv; psq[r] += xv*xv;
        }
    }
    #pragma unroll
    for (int off = 1; off < 16; off <<= 1){
        #pragma unroll
        for (int r = 0; r < 4; ++r){ psum[r] += __shfl_xor(psum[r], off); psq[r] += __shfl_xor(psq[r], off); }
    }
    if (li == 0){
        #pragma unroll
        for (int r = 0; r < 4; ++r){ redS[w][qd][r] = psum[r]; redQ[w][qd][r] = psq[r]; }
    }
    __syncthreads();
    float mean[4], rstd[4];
    #pragma unroll
    for (int r = 0; r < 4; ++r){
        float sm = redS[0][qd][r] + redS[1][qd][r] + redS[2][qd][r] + redS[3][qd][r];
        float sq = redQ[0][qd][r] + redQ[1][qd][r] + redQ[2][qd][r] + redQ[3][qd][r];
        mean[r] = sm * (1.0f/512.0f);
        float var = sq * (1.0f/512.0f) - mean[r]*mean[r];
        rstd[r] = rsqrtf(var + 1e-5f);
    }
    #pragma unroll
    for (int c = 0; c < 8; ++c){
        #pragma unroll
        for (int r = 0; r < 4; ++r){
            int m = qd*4 + r, n = w*128 + c*16 + li;
            float hn = (v[c][r] - mean[r])*rstd[r]*g[n] + be[n];
            h[(size_t)(m0 + m)*512 + n] = hn;
            hbf[(size_t)(m0 + m)*512 + n] = __float2bfloat16(hn);
        }
    }
}

__global__ __launch_bounds__(256)
void ln2he_k(const float* __restrict__ tmp, const float* __restrict__ g,
             const float* __restrict__ be, float* __restrict__ h,
             __hip_bfloat16* __restrict__ hbf,
             const float* __restrict__ hw, const float* __restrict__ hb,
             const float* __restrict__ x, const float* __restrict__ ip_w,
             const float* __restrict__ ip_b, float* __restrict__ out,
             int t, int dohead)
{
    int b = blockIdx.x, tid = threadIdx.x;
    __shared__ float red[4];
    __shared__ float hred[4][3];
    __shared__ float ybc[3];
    float x0 = tmp[(size_t)b*512 + tid];
    float x1 = tmp[(size_t)b*512 + 256 + tid];
    float s = x0 + x1;
    #pragma unroll
    for (int off = 32; off; off >>= 1) s += __shfl_xor(s, off);
    if ((tid & 63) == 0) red[tid >> 6] = s;
    __syncthreads();
    float mean = (red[0] + red[1] + red[2] + red[3]) * (1.0f/512.0f);
    float d0 = x0 - mean, d1 = x1 - mean;
    float vs = d0*d0 + d1*d1;
    #pragma unroll
    for (int off = 32; off; off >>= 1) vs += __shfl_xor(vs, off);
    __syncthreads();
    if ((tid & 63) == 0) red[tid >> 6] = vs;
    __syncthreads();
    float var = (red[0] + red[1] + red[2] + red[3]) * (1.0f/512.0f);
    float r = rsqrtf(var + 1e-5f);
    float n0_ = d0*r*g[tid]       + be[tid];
    float n1_ = d1*r*g[256 + tid] + be[256 + tid];
    if (!dohead){
        h[(size_t)b*512 + tid] = n0_;
        h[(size_t)b*512 + 256 + tid] = n1_;
        hbf[(size_t)b*512 + tid] = __float2bfloat16(n0_);
        hbf[(size_t)b*512 + 256 + tid] = __float2bfloat16(n1_);
        return;
    }
    float s0 = n0_*hw[tid*3]     + n1_*hw[(tid+256)*3];
    float s1 = n0_*hw[tid*3 + 1] + n1_*hw[(tid+256)*3 + 1];
    float s2 = n0_*hw[tid*3 + 2] + n1_*hw[(tid+256)*3 + 2];
    #pragma unroll
    for (int off = 32; off; off >>= 1){
        s0 += __shfl_xor(s0, off); s1 += __shfl_xor(s1, off); s2 += __shfl_xor(s2, off);
    }
    int w = tid >> 6;
    if ((tid & 63) == 0){ hred[w][0] = s0; hred[w][1] = s1; hred[w][2] = s2; }
    __syncthreads();
    if (tid < 3){
        float y = hred[0][tid] + hred[1][tid] + hred[2][tid] + hred[3][tid] + hb[tid];
        out[((size_t)b*16 + t)*3 + tid] = y;
        ybc[tid] = y;
    }
    __syncthreads();
    if (t < 15){
        float y0 = ybc[0], y1 = ybc[1], y2 = ybc[2];
        #pragma unroll
        for (int half = 0; half < 2; ++half){
            int d = tid + half*256;
            int e = d & ~1;
            float div = expf(-(float)e * (9.210340371976184f / 512.0f));
            float arg = (float)(t + 1) * div;
            float pe = (d & 1) ? cosf(arg) : sinf(arg);
            float acc = ip_b[d] + pe;
            #pragma unroll
            for (int i = 0; i < 4; ++i)
                acc += x[((size_t)b*16 + t + 1)*7 + i] * ip_w[i*512 + d];
            acc += y0*ip_w[4*512 + d] + y1*ip_w[5*512 + d] + y2*ip_w[6*512 + d];
            h[(size_t)b*512 + d] = acc;
            hbf[(size_t)b*512 + d] = __float2bfloat16(acc);
        }
    }
}

// ===========================================================================
// Mega kernel: persistent, hand-rolled grid barrier
// ===========================================================================
__device__ __forceinline__ void gemm_tile(
    const uint4* __restrict__ Ag, const uint4* __restrict__ Bg,
    int Kg, int N, int kb0, int kb1, int m0, int n0, int tid,
    floatx4 acc[2][2], uint4* ldsA, uint4* ldsB)
{
    int lane = tid & 63, w = tid >> 6;
    int am = tid >> 2, aq = tid & 3;
    int bq = w, bn = tid & 63;
    int rh = w & 1, ch = w >> 1;
    int qd = lane >> 4, li = lane & 15;
    for (int kb = kb0; kb < kb1; ++kb){
        __syncthreads();
        ldsA[aq*64 + am] = Ag[(size_t)(m0 + am)*Kg + kb*4 + aq];
        ldsB[bq*64 + bn] = Bg[(size_t)(kb*4 + bq)*N + n0 + bn];
        __syncthreads();
        short8 af0 = as_short8(ldsA[qd*64 + rh*32 +      li]);
        short8 af1 = as_short8(ldsA[qd*64 + rh*32 + 16 + li]);
        short8 bf0 = as_short8(ldsB[qd*64 + ch*32 +      li]);
        short8 bf1 = as_short8(ldsB[qd*64 + ch*32 + 16 + li]);
        acc[0][0] = __builtin_amdgcn_mfma_f32_16x16x32_bf16(af0, bf0, acc[0][0], 0, 0, 0);
        acc[0][1] = __builtin_amdgcn_mfma_f32_16x16x32_bf16(af0, bf1, acc[0][1], 0, 0, 0);
        acc[1][0] = __builtin_amdgcn_mfma_f32_16x16x32_bf16(af1, bf0, acc[1][0], 0, 0, 0);
        acc[1][1] = __builtin_amdgcn_mfma_f32_16x16x32_bf16(af1, bf1, acc[1][1], 0, 0, 0);
    }
}

__global__ __launch_bounds__(256)
void mega_k(const float* __restrict__ x, const ushort* __restrict__ wsw,
            const float* __restrict__ ip_w, const float* __restrict__ ip_b,
            const float* __restrict__ qkv_b, const float* __restrict__ out_b,
            const float* __restrict__ ln1_s, const float* __restrict__ ln1_b,
            const float* __restrict__ ff_b1, const float* __restrict__ ff_b2,
            const float* __restrict__ ln2_s, const float* __restrict__ ln2_b,
            const float* __restrict__ hw, const float* __restrict__ hb,
            float* __restrict__ out,
            float* __restrict__ pbuf, float* __restrict__ h,
            __hip_bfloat16* __restrict__ hbf, __hip_bfloat16* __restrict__ attnbf,
            __hip_bfloat16* __restrict__ ffbf,
            __hip_bfloat16* __restrict__ kc, __hip_bfloat16* __restrict__ vc)
{
    __shared__ union {
        struct { uint4 a[256]; uint4 b[256]; } g;
        uint4 slab[64*17 + 1];
    } sh;
    __shared__ float redS[4][4][4], redQ[4][4][4];
    __shared__ float redA[4];
    __shared__ float hred[4][3];
    __shared__ float ybc[3];

    float* qbuf = pbuf + 262144;   // alias: dead before ff2 partial-1 write

    int blk = blockIdx.x, tid = threadIdx.x;
    int lane = tid & 63, w = tid >> 6;
    int rh = w & 1, ch = w >> 1;
    int qd = lane >> 4, li = lane & 15;

    // ---- t=0 embed
    #pragma unroll
    for (int rr = 0; rr < 2; ++rr){
        int b = blk*2 + rr;
        #pragma unroll
        for (int half = 0; half < 2; ++half){
            int d = tid + half*256;
            float pe = (d & 1) ? 1.0f : 0.0f;
            float acc = ip_b[d] + pe;
            #pragma unroll
            for (int i = 0; i < 7; ++i)
                acc += x[(b*16 + 0)*7 + i] * ip_w[i*512 + d];
            h[b*512 + d] = acc;
            hbf[b*512 + d] = __float2bfloat16(acc);
        }
    }
    gridbar();

    for (int t = 0; t < 16; ++t){
        for (int l = 0; l < 2; ++l){
            // -------- P1: QKV GEMM (192 tiles) --------
            if (blk < 192){
                int m0 = (blk / 24) * 64, n0 = (blk % 24) * 64;
                floatx4 acc[2][2] = {};
                gemm_tile((const uint4*)hbf, (const uint4*)(wsw + (size_t)l*786432),
                          64, 1536, 0, 16, m0, n0, tid, acc, sh.g.a, sh.g.b);
                const float* qb = qkv_b + l*1536;
                __hip_bfloat16* kcl = kc + (size_t)l*4194304;
                __hip_bfloat16* vcl = vc + (size_t)l*4194304;
                #pragma unroll
                for (int i = 0; i < 2; ++i){
                    #pragma unroll
                    for (int j = 0; j < 2; ++j){
                        #pragma unroll
                        for (int r = 0; r < 4; ++r){
                            int m = m0 + rh*32 + i*16 + qd*4 + r;
                            int n = n0 + ch*32 + j*16 + li;
                            float v = acc[i][j][r] + qb[n];
                            if (n < 512){
                                qbuf[m*512 + n] = v;
                            } else if (n < 1024){
                                int z = n - 512;
                                kcl[((m*8 + (z >> 6))*16 + t)*64 + (z & 63)] = __float2bfloat16(v);
                            } else {
                                int z = n - 1024;
                                vcl[((m*8 + (z >> 6))*16 + t)*64 + (z & 63)] = __float2bfloat16(v);
                            }
                        }
                    }
                }
            }
            gridbar();

            // -------- P2: attention --------
            {
                const __hip_bfloat16* kcl = kc + (size_t)l*4194304;
                const __hip_bfloat16* vcl = vc + (size_t)l*4194304;
                #pragma unroll
                for (int p = 0; p < 4; ++p){
                    int pair = (blk*4 + w)*4 + p;
                    int b = pair >> 3, hh = pair & 7;
                    float qv = qbuf[b*512 + hh*64 + lane];
                    const __hip_bfloat16* kp = kcl + ((size_t)b*8 + hh)*1024;
                    const __hip_bfloat16* vp = vcl + ((size_t)b*8 + hh)*1024;
                    float m_ = -1e30f, s_ = 0.0f, o_ = 0.0f;
                    for (int j = 0; j <= t; ++j){
                        float pq = qv * __bfloat162float(kp[j*64 + lane]);
                        #pragma unroll
                        for (int off = 32; off; off >>= 1) pq += __shfl_xor(pq, off);
                        pq *= 0.125f;
                        float nm = fmaxf(m_, pq);
                        float sc = expf(m_ - nm);
                        float e  = expf(pq - nm);
                        s_ = s_*sc + e;
                        o_ = o_*sc + e*__bfloat162float(vp[j*64 + lane]);
                        m_ = nm;
                    }
                    attnbf[b*512 + hh*64 + lane] = __float2bfloat16(o_ / s_);
                }
            }
            gridbar();

            // -------- P3: out-proj + bias + resid + LN1 (32 row-blocks) ----
            if (blk < 32){
                int m0 = blk*16;
                const uint4* Ag = (const uint4*)attnbf;
                #pragma unroll
                for (int it = 0; it < 4; ++it){
                    int m = it*4 + w;
                    sh.slab[lane*17 + m] = Ag[(size_t)(m0 + m)*64 + lane];
                }
                __syncthreads();
                const uint4* Bg = (const uint4*)(wsw + 1572864 + (size_t)l*262144);
                floatx4 acc[8] = {};
                for (int kb = 0; kb < 16; ++kb){
                    short8 af = as_short8(sh.slab[(kb*4 + qd)*17 + li]);
                    #pragma unroll
                    for (int c = 0; c < 8; ++c){
                        int n = w*128 + c*16 + li;
                        short8 bfv = as_short8(Bg[(size_t)(kb*4 + qd)*512 + n]);
                        acc[c] = __builtin_amdgcn_mfma_f32_16x16x32_bf16(af, bfv, acc[c], 0, 0, 0);
                    }
                }
                const float* ob = out_b + l*512;
                const float* g  = ln1_s + l*512;
                const float* be = ln1_b + l*512;
                float v[8][4];
                float psum[4] = {}, psq[4] = {};
                #pragma unroll
                for (int c = 0; c < 8; ++c){
                    #pragma unroll
                    for (int r = 0; r < 4; ++r){
                        int m = qd*4 + r, n = w*128 + c*16 + li;
                        float xv = acc[c][r] + ob[n] + h[(size_t)(m0 + m)*512 + n];
                        v[c][r] = xv; psum[r] += xv; psq[r] += xv*xv;
                    }
                }
                #pragma unroll
                for (int off = 1; off < 16; off <<= 1){
                    #pragma unroll
                    for (int r = 0; r < 4; ++r){ psum[r] += __shfl_xor(psum[r], off); psq[r] += __shfl_xor(psq[r], off); }
                }
                if (li == 0){
                    #pragma unroll
                    for (int r = 0; r < 4; ++r){ redS[w][qd][r] = psum[r]; redQ[w][qd][r] = psq[r]; }
                }
                __syncthreads();
                float mean[4], rstd[4];
                #pragma unroll
                for (int r = 0; r < 4; ++r){
                    float sm = redS[0][qd][r] + redS[1][qd][r] + redS[2][qd][r] + redS[3][qd][r];
                    float sq = redQ[0][qd][r] + redQ[1][qd][r] + redQ[2][qd][r] + redQ[3][qd][r];
                    mean[r] = sm * (1.0f/512.0f);
                    float var = sq * (1.0f/512.0f) - mean[r]*mean[r];
                    rstd[r] = rsqrtf(var + 1e-5f);
                }
                #pragma unroll
                for (int c = 0; c < 8; ++c){
                    #pragma unroll
                    for (int r = 0; r < 4; ++r){
                        int m = qd*4 + r, n = w*128 + c*16 + li;
                        float hn = (v[c][r] - mean[r])*rstd[r]*g[n] + be[n];
                        h[(size_t)(m0 + m)*512 + n] = hn;
                        hbf[(size_t)(m0 + m)*512 + n] = __float2bfloat16(hn);
                    }
                }
            }
            gridbar();

            // -------- P4: FF1 + relu (256 tiles) --------
            {
                int m0 = (blk >> 5) * 64, n0 = (blk & 31) * 64;
                floatx4 acc[2][2] = {};
                gemm_tile((const uint4*)hbf, (const uint4*)(wsw + 2097152 + (size_t)l*1048576),
                          64, 2048, 0, 16, m0, n0, tid, acc, sh.g.a, sh.g.b);
                const float* fb = ff_b1 + l*2048;
                #pragma unroll
                for (int i = 0; i < 2; ++i){
                    #pragma unroll
                    for (int j = 0; j < 2; ++j){
                        #pragma unroll
                        for (int r = 0; r < 4; ++r){
                            int m = m0 + rh*32 + i*16 + qd*4 + r;
                            int n = n0 + ch*32 + j*16 + li;
                            float v = acc[i][j][r] + fb[n];
                            ffbf[(size_t)m*2048 + n] = __float2bfloat16(fmaxf(v, 0.0f));
                        }
                    }
                }
            }
            gridbar();

            // -------- P5: FF2 split-K=2 (128 blocks) --------
            if (blk < 128){
                int tile = blk >> 1, ks = blk & 1;
                int m0 = (tile >> 3) * 64, n0 = (tile & 7) * 64;
                floatx4 acc[2][2] = {};
                gemm_tile((const uint4*)ffbf, (const uint4*)(wsw + 4194304 + (size_t)l*1048576),
                          256, 512, ks*32, ks*32 + 32, m0, n0, tid, acc, sh.g.a, sh.g.b);
                float* pp = pbuf + ks*262144;
                #pragma unroll
                for (int i = 0; i < 2; ++i){
                    #pragma unroll
                    for (int j = 0; j < 2; ++j){
                        #pragma unroll
                        for (int r = 0; r < 4; ++r){
                            int m = m0 + rh*32 + i*16 + qd*4 + r;
                            int n = n0 + ch*32 + j*16 + li;
                            pp[m*512 + n] = acc[i][j][r];
                        }
                    }
                }
            }
            gridbar();

            // -------- P6: LN2 (+head+embed on l==1) --------
            {
                const float* g  = ln2_s + l*512;
                const float* be = ln2_b + l*512;
                const float* fb = ff_b2 + l*512;
                #pragma unroll
                for (int rr = 0; rr < 2; ++rr){
                    int b = blk*2 + rr;
                    float v0 = pbuf[b*512 + tid]       + pbuf[262144 + b*512 + tid]
                             + fb[tid]       + h[b*512 + tid];
                    float v1 = pbuf[b*512 + 256 + tid] + pbuf[262144 + b*512 + 256 + tid]
                             + fb[256 + tid] + h[b*512 + 256 + tid];
                    float s = v0 + v1;
                    #pragma unroll
                    for (int off = 32; off; off >>= 1) s += __shfl_xor(s, off);
                    __syncthreads();
                    if ((tid & 63) == 0) redA[w] = s;
                    __syncthreads();
                    float mean = (redA[0] + redA[1] + redA[2] + redA[3]) * (1.0f/512.0f);
                    float d0 = v0 - mean, d1 = v1 - mean;
                    float vs = d0*d0 + d1*d1;
                    #pragma unroll
                    for (int off = 32; off; off >>= 1) vs += __shfl_xor(vs, off);
                    __syncthreads();
                    if ((tid & 63) == 0) redA[w] = vs;
                    __syncthreads();
                    float var = (redA[0] + redA[1] + redA[2] + redA[3]) * (1.0f/512.0f);
                    float r = rsqrtf(var + 1e-5f);
                    float n0_ = d0*r*g[tid]       + be[tid];
                    float n1_ = d1*r*g[256 + tid] + be[256 + tid];
                    if (l == 0){
                        h[b*512 + tid]       = n0_;
                        h[b*512 + 256 + tid] = n1_;
                        hbf[b*512 + tid]       = __float2bfloat16(n0_);
                        hbf[b*512 + 256 + tid] = __float2bfloat16(n1_);
                    } else {
                        float s0 = n0_*hw[tid*3]     + n1_*hw[(tid+256)*3];
                        float s1 = n0_*hw[tid*3 + 1] + n1_*hw[(tid+256)*3 + 1];
                        float s2 = n0_*hw[tid*3 + 2] + n1_*hw[(tid+256)*3 + 2];
                        #pragma unroll
                        for (int off = 32; off; off >>= 1){
                            s0 += __shfl_xor(s0, off);
                            s1 += __shfl_xor(s1, off);
                            s2 += __shfl_xor(s2, off);
                        }
                        __syncthreads();
                        if ((tid & 63) == 0){ hred[w][0] = s0; hred[w][1] = s1; hred[w][2] = s2; }
                        __syncthreads();
                        if (tid < 3){
                            float y = hred[0][tid] + hred[1][tid] + hred[2][tid] + hred[3][tid] + hb[tid];
                            out[(b*16 + t)*3 + tid] = y;
                            ybc[tid] = y;
                        }
                        __syncthreads();
                        if (t < 15){
                            float y0 = ybc[0], y1 = ybc[1], y2 = ybc[2];
                            #pragma unroll
                            for (int half = 0; half < 2; ++half){
                                int d = tid + half*256;
                                int e = d & ~1;
                                float div = expf(-(float)e * (9.210340371976184f / 512.0f));
                                float arg = (float)(t + 1) * div;
                                float pe = (d & 1) ? cosf(arg) : sinf(arg);
                                float acc = ip_b[d] + pe;
                                #pragma unroll
                                for (int i = 0; i < 4; ++i)
                                    acc += x[(b*16 + t + 1)*7 + i] * ip_w[i*512 + d];
                                acc += y0*ip_w[4*512 + d] + y1*ip_w[5*512 + d] + y2*ip_w[6*512 + d];
                                h[b*512 + d] = acc;
                                hbf[b*512 + d] = __float2bfloat16(acc);
                            }
                        }
                        __syncthreads();
                    }
                }
            }
            gridbar();
        }
    }
}

// ---------------------------------------------------------------------------
extern "C" void kernel_launch(void* const* d_in, const int* in_sizes, int n_in,
                              void* d_out, int out_size, void* d_ws, size_t ws_size,
                              hipStream_t stream)
{
    const float* x     = (const float*)d_in[0];
    const float* ip_w  = (const float*)d_in[1];
    const float* ip_b  = (const float*)d_in[2];
    const float* qkv_w = (const float*)d_in[3];
    const float* qkv_b = (const float*)d_in[4];
    const float* out_w = (const float*)d_in[5];
    const float* out_b = (const float*)d_in[6];
    const float* ln1_s = (const float*)d_in[7];
    const float* ln1_b = (const float*)d_in[8];
    const float* ff_w1 = (const float*)d_in[9];
    const float* ff_b1 = (const float*)d_in[10];
    const float* ff_w2 = (const float*)d_in[11];
    const float* ff_b2 = (const float*)d_in[12];
    const float* ln2_s = (const float*)d_in[13];
    const float* ln2_b = (const float*)d_in[14];
    const float* hw    = (const float*)d_in[15];
    const float* hb    = (const float*)d_in[16];
    float* out = (float*)d_out;

    // ws layout (bytes): wsw 12,582,912 | pbuf 2M | h 1M | hbf 0.5M |
    //                    attnbf 0.5M | ffbf 2M | kc 16M | vc 16M = 50 MB
    ushort* wsw = (ushort*)d_ws;
    float* pbuf = (float*)((char*)d_ws + 12582912);
    float* h    = pbuf + 524288;
    __hip_bfloat16* hbf    = (__hip_bfloat16*)(h + 262144);
    __hip_bfloat16* attnbf = hbf + 262144;
    __hip_bfloat16* ffbf   = attnbf + 262144;
    __hip_bfloat16* kc     = ffbf + 1048576;
    __hip_bfloat16* vc     = kc + 8388608;
    float* tmp  = pbuf;
    float* qbuf = pbuf + 262144;
    const int CPL = 4194304;

    swz_k<<<dim3(32, 64, 8), 256, 0, stream>>>(qkv_w, out_w, ff_w1, ff_w2, wsw);

    void* args[] = {
        (void*)&x, (void*)&wsw, (void*)&ip_w, (void*)&ip_b,
        (void*)&qkv_b, (void*)&out_b, (void*)&ln1_s, (void*)&ln1_b,
        (void*)&ff_b1, (void*)&ff_b2, (void*)&ln2_s, (void*)&ln2_b,
        (void*)&hw, (void*)&hb, (void*)&out,
        (void*)&pbuf, (void*)&h, (void*)&hbf, (void*)&attnbf, (void*)&ffbf,
        (void*)&kc, (void*)&vc
    };
    hipError_t err = hipLaunchCooperativeKernel((void*)mega_k, dim3(NBLK), dim3(256),
                                                args, 0, stream);
    if (err != hipSuccess){
        // Fallback: verified round-2 multi-kernel path.
        embed0_k<<<1024, 256, 0, stream>>>(x, ip_w, ip_b, h, hbf);
        for (int t = 0; t < 16; ++t){
            for (int l = 0; l < 2; ++l){
                gemm64_k<0><<<dim3(24, 8), 256, 0, stream>>>(
                    hbf, wsw + (size_t)l*786432, qkv_b + l*1536, t,
                    qbuf, kc + (size_t)l*CPL, vc + (size_t)l*CPL,
                    nullptr, nullptr, nullptr);
                attn_k<<<1024, 256, 0, stream>>>(qbuf, kc + (size_t)l*CPL, vc + (size_t)l*CPL, attnbf, t);
                outln_k<<<32, 256, 0, stream>>>(
                    attnbf, wsw + 1572864 + (size_t)l*262144, out_b + l*512,
                    ln1_s + l*512, ln1_b + l*512, h, hbf);
                gemm64_k<1><<<dim3(32, 8), 256, 0, stream>>>(
                    hbf, wsw + 2097152 + (size_t)l*1048576, ff_b1 + l*2048, t,
                    nullptr, nullptr, nullptr, ffbf, nullptr, nullptr);
                gemm64_k<2><<<dim3(8, 8), 256, 0, stream>>>(
                    ffbf, wsw + 4194304 + (size_t)l*1048576, ff_b2 + l*512, t,
                    nullptr, nullptr, nullptr, nullptr, tmp, h);
                ln2he_k<<<512, 256, 0, stream>>>(
                    tmp, ln2_s + l*512, ln2_b + l*512, h, hbf,
                    hw, hb, x, ip_w, ip_b, out, t, l == 1);
            }
        }
    }
}